// Round 7
// baseline (248.374 us; speedup 1.0000x reference)
//
#include <hip/hip_runtime.h>
#include <hip/hip_cooperative_groups.h>

namespace cg = cooperative_groups;

#define W 512
#define NPIX 4194304              // 16 images * 512*512, per input

union Bytes { uint4 v; unsigned char b[16]; };

__device__ __forceinline__ unsigned char gray1(float a, float b, float c) {
    // JAX f32 op order: ((c0+c1+c2)/3)*255, round-nearest-even
    return (unsigned char)__float2int_rn(((a + b + c) / 3.0f) * 255.0f);
}

// ===========================================================================
// PRIMARY: one cooperative kernel, grid 512 x 1, block 256.
//   block = one (img, 16-row tile); handles BOTH inputs (two LDS tiles).
//   SHIFTS=(1,0),(1,1),(0,1),(-1,1); shifted[r,c]=g[(r-dx)&511,(c-dy)&511]
// Phase A: gray rows r0-1..r0+16 (18 rows, halo recomputed) -> LDS, both
//          inputs; per-block min/max of joint per (input,shift) ->
//          atomicExch to distinct global slots (R4-proven coherence pattern).
// grid.sync()
// Phase B: redundantly reduce the 16x512 minmax table (L2-resident);
//          contrast from the SAME LDS tiles: b = clip(floor((joint-vmin)*
//          scale),0,65535) exact f32 histc emu, d=(b>>8)-(b&255);
//          per-block sum d^2 -> atomicExch to distinct slots.
// grid.sync()
// Phase C: block 0 reduces 8x512 partials (double, exact) -> loss.
// Only scalars live in registers across syncs (R4 spill lesson).
// ===========================================================================
__global__ __launch_bounds__(256, 2) void fused(
    const float4* __restrict__ og, const float4* __restrict__ gg,
    unsigned int* __restrict__ blockmm, unsigned int* __restrict__ partial,
    float* __restrict__ out) {
    cg::grid_group grid = cg::this_grid();
    int img = blockIdx.x >> 5;
    int r0 = (blockIdx.x & 31) << 4;

    __shared__ unsigned char lds[2][18 * W];      // 18,432 B
    __shared__ unsigned int wtmin[4][4], wtmax[4][4];
    __shared__ unsigned int mmfin[16];
    __shared__ double cs[8];

    // ---- Phase A: gray tiles for both inputs ----
    for (int inp = 0; inp < 2; ++inp) {
        const float4* src = (inp ? gg : og) + (size_t)img * 3 * 65536;
        uchar4* l4 = (uchar4*)lds[inp];
#pragma unroll
        for (int j = 0; j < 9; ++j) {
            int q = threadIdx.x + j * 256;        // 18 rows * 128 quads
            int i = q >> 7, quad = q & 127;
            int ir = (r0 - 1 + i) & 511;
            float4 a = src[(size_t)ir * 128 + quad];
            float4 b = src[65536 + (size_t)ir * 128 + quad];
            float4 c = src[131072 + (size_t)ir * 128 + quad];
            uchar4 r;
            r.x = gray1(a.x, b.x, c.x);
            r.y = gray1(a.y, b.y, c.y);
            r.z = gray1(a.z, b.z, c.z);
            r.w = gray1(a.w, b.w, c.w);
            l4[q] = r;
        }
    }
    __syncthreads();

    int lr = 1 + (threadIdx.x >> 4);              // lds row 1..16
    int c0 = (threadIdx.x & 15) << 5;             // col 0..480
    int cp = (c0 - 1) & 511;
    int wave = threadIdx.x >> 6;

    // ---- Phase A cont.: min/max per (input, shift) ----
    for (int inp = 0; inp < 2; ++inp) {
        const unsigned char* Lm = lds[inp] + (lr - 1) * W;
        const unsigned char* Lc = lds[inp] + lr * W;
        const unsigned char* Lp = lds[inp] + (lr + 1) * W;
        Bytes rm[2], rc[2], rp[2];
        rm[0].v = *(const uint4*)(Lm + c0); rm[1].v = *(const uint4*)(Lm + c0 + 16);
        rc[0].v = *(const uint4*)(Lc + c0); rc[1].v = *(const uint4*)(Lc + c0 + 16);
        rp[0].v = *(const uint4*)(Lp + c0); rp[1].v = *(const uint4*)(Lp + c0 + 16);
        unsigned char pm = Lm[cp], pc = Lc[cp], pp = Lp[cp];

        unsigned int lmin[4] = {~0u, ~0u, ~0u, ~0u};
        unsigned int lmax[4] = {0u, 0u, 0u, 0u};
#pragma unroll
        for (int h = 0; h < 2; ++h) {
#pragma unroll
            for (int j = 0; j < 16; ++j) {
                unsigned int base = ((unsigned int)rc[h].b[j]) << 8;
                unsigned int v0 = base + rm[h].b[j];
                unsigned int v1 = base + (j ? rm[h].b[j - 1] : (h ? rm[0].b[15] : pm));
                unsigned int v2 = base + (j ? rc[h].b[j - 1] : (h ? rc[0].b[15] : pc));
                unsigned int v3 = base + (j ? rp[h].b[j - 1] : (h ? rp[0].b[15] : pp));
                lmin[0] = min(lmin[0], v0); lmax[0] = max(lmax[0], v0);
                lmin[1] = min(lmin[1], v1); lmax[1] = max(lmax[1], v1);
                lmin[2] = min(lmin[2], v2); lmax[2] = max(lmax[2], v2);
                lmin[3] = min(lmin[3], v3); lmax[3] = max(lmax[3], v3);
            }
        }
#pragma unroll
        for (int off = 32; off > 0; off >>= 1) {
#pragma unroll
            for (int s = 0; s < 4; ++s) {
                lmin[s] = min(lmin[s], (unsigned int)__shfl_down((int)lmin[s], off));
                lmax[s] = max(lmax[s], (unsigned int)__shfl_down((int)lmax[s], off));
            }
        }
        if ((threadIdx.x & 63) == 0) {
#pragma unroll
            for (int s = 0; s < 4; ++s) { wtmin[wave][s] = lmin[s]; wtmax[wave][s] = lmax[s]; }
        }
        __syncthreads();
        if (threadIdx.x < 4) {
            int s = threadIdx.x;
            unsigned int mn = min(min(wtmin[0][s], wtmin[1][s]), min(wtmin[2][s], wtmin[3][s]));
            unsigned int mx = max(max(wtmax[0][s], wtmax[1][s]), max(wtmax[2][s], wtmax[3][s]));
            atomicExch(&blockmm[inp * 4096 + s * 512 + blockIdx.x], mn);
            atomicExch(&blockmm[inp * 4096 + (4 + s) * 512 + blockIdx.x], mx);
        }
        __syncthreads();   // before reusing wtmin/wtmax
    }
    __threadfence();
    grid.sync();
    __threadfence();

    // ---- Phase B: reduce minmax table (16 combos x 512, L2-resident) ----
    {
        int c = threadIdx.x >> 4, lane = threadIdx.x & 15;   // c = inp*8 + row
        int row = c & 7;
        const unsigned int* mb = blockmm + c * 512;
        unsigned int v = mb[lane];
#pragma unroll
        for (int k = 1; k < 32; ++k) {
            unsigned int u = mb[lane + k * 16];
            v = (row < 4) ? min(v, u) : max(v, u);
        }
#pragma unroll
        for (int off = 8; off > 0; off >>= 1) {
            unsigned int u = (unsigned int)__shfl_down((int)v, off, 16);
            v = (row < 4) ? min(v, u) : max(v, u);
        }
        if (lane == 0) mmfin[c] = v;
    }
    __syncthreads();

    // ---- Phase B cont.: contrast from LDS tiles ----
    for (int inp = 0; inp < 2; ++inp) {
        unsigned int vm[4]; float scale[4];
#pragma unroll
        for (int s = 0; s < 4; ++s) {
            vm[s] = mmfin[inp * 8 + s];
            scale[s] = 65536.0f / fmaxf((float)(mmfin[inp * 8 + 4 + s] - vm[s]), 1.0f);
        }
        const unsigned char* Lm = lds[inp] + (lr - 1) * W;
        const unsigned char* Lc = lds[inp] + lr * W;
        const unsigned char* Lp = lds[inp] + (lr + 1) * W;
        Bytes rm[2], rc[2], rp[2];
        rm[0].v = *(const uint4*)(Lm + c0); rm[1].v = *(const uint4*)(Lm + c0 + 16);
        rc[0].v = *(const uint4*)(Lc + c0); rc[1].v = *(const uint4*)(Lc + c0 + 16);
        rp[0].v = *(const uint4*)(Lp + c0); rp[1].v = *(const uint4*)(Lp + c0 + 16);
        unsigned char pm = Lm[cp], pc = Lc[cp], pp = Lp[cp];

        unsigned int acc[4] = {0u, 0u, 0u, 0u};
#pragma unroll
        for (int h = 0; h < 2; ++h) {
#pragma unroll
            for (int j = 0; j < 16; ++j) {
                unsigned int base = ((unsigned int)rc[h].b[j]) << 8;
                unsigned int v[4];
                v[0] = base + rm[h].b[j];
                v[1] = base + (j ? rm[h].b[j - 1] : (h ? rm[0].b[15] : pm));
                v[2] = base + (j ? rc[h].b[j - 1] : (h ? rc[0].b[15] : pc));
                v[3] = base + (j ? rp[h].b[j - 1] : (h ? rp[0].b[15] : pp));
#pragma unroll
                for (int s = 0; s < 4; ++s) {
                    int b = (int)floorf((float)(v[s] - vm[s]) * scale[s]);
                    b = b < 0 ? 0 : (b > 65535 ? 65535 : b);
                    int d = (b >> 8) - (b & 255);
                    acc[s] += (unsigned int)(d * d);
                }
            }
        }
#pragma unroll
        for (int off = 32; off > 0; off >>= 1)
#pragma unroll
            for (int s = 0; s < 4; ++s)
                acc[s] += (unsigned int)__shfl_down((int)acc[s], off);

        if ((threadIdx.x & 63) == 0) {
#pragma unroll
            for (int s = 0; s < 4; ++s) wtmin[wave][s] = acc[s];
        }
        __syncthreads();
        if (threadIdx.x < 4) {
            int s = threadIdx.x;
            unsigned int tot = wtmin[0][s] + wtmin[1][s] + wtmin[2][s] + wtmin[3][s];
            atomicExch(&partial[(inp * 4 + s) * 512 + blockIdx.x], tot);
        }
        __syncthreads();
    }
    __threadfence();
    grid.sync();
    __threadfence();

    // ---- Phase C: block 0 reduces partials, writes loss ----
    if (blockIdx.x == 0) {
        int c = threadIdx.x >> 5;         // combo = inp*4 + s
        int lane = threadIdx.x & 31;
        const unsigned int* p = partial + c * 512;
        double acc = 0.0;
#pragma unroll
        for (int k = 0; k < 16; ++k) acc += (double)p[lane + k * 32];
#pragma unroll
        for (int off = 16; off > 0; off >>= 1) acc += __shfl_down(acc, off, 32);
        if (lane == 0) cs[c] = acc;
        __syncthreads();
        if (threadIdx.x == 0) {
            double r = 0.0;
            for (int a = 0; a < 4; ++a) {
                double co = 2.0 * cs[a]     / 33554432.0;
                double cg = 2.0 * cs[4 + a] / 33554432.0;
                r += fabs(co - cg);
            }
            out[0] = (float)(r * 0.25);
        }
    }
}

// ===========================================================================
// FALLBACK path (R5's proven 3-kernel pipeline, 41 us) — used only if the
// cooperative launch is rejected by the runtime.
// ===========================================================================
__global__ __launch_bounds__(256) void k1_gray_minmax(
    const float4* __restrict__ og, const float4* __restrict__ gg,
    uchar4* __restrict__ gray, unsigned int* __restrict__ blockmm) {
    int inp = blockIdx.y;
    int img = blockIdx.x >> 5;
    int r0 = (blockIdx.x & 31) << 4;
    const float4* src = (inp ? gg : og) + (size_t)img * 3 * 65536;
    uchar4* gout = gray + (size_t)inp * (NPIX / 4) + img * 65536;

    __shared__ unsigned char lds[18 * W];
    uchar4* lds4 = (uchar4*)lds;
#pragma unroll
    for (int j = 0; j < 9; ++j) {
        int q = threadIdx.x + j * 256;
        int i = q >> 7, quad = q & 127;
        int ir = (r0 - 1 + i) & 511;
        float4 a = src[(size_t)ir * 128 + quad];
        float4 b = src[65536 + (size_t)ir * 128 + quad];
        float4 c = src[131072 + (size_t)ir * 128 + quad];
        uchar4 r;
        r.x = gray1(a.x, b.x, c.x);
        r.y = gray1(a.y, b.y, c.y);
        r.z = gray1(a.z, b.z, c.z);
        r.w = gray1(a.w, b.w, c.w);
        lds4[q] = r;
        if (i >= 1 && i <= 16) gout[ir * 128 + quad] = r;
    }
    __syncthreads();

    int lr = 1 + (threadIdx.x >> 4);
    int c0 = (threadIdx.x & 15) << 5;
    const unsigned char* Lm = lds + (lr - 1) * W;
    const unsigned char* Lc = lds + lr * W;
    const unsigned char* Lp = lds + (lr + 1) * W;
    Bytes rm[2], rc[2], rp[2];
    rm[0].v = *(const uint4*)(Lm + c0); rm[1].v = *(const uint4*)(Lm + c0 + 16);
    rc[0].v = *(const uint4*)(Lc + c0); rc[1].v = *(const uint4*)(Lc + c0 + 16);
    rp[0].v = *(const uint4*)(Lp + c0); rp[1].v = *(const uint4*)(Lp + c0 + 16);
    int cp = (c0 - 1) & 511;
    unsigned char pm = Lm[cp], pc = Lc[cp], pp = Lp[cp];

    unsigned int lmin[4] = {~0u, ~0u, ~0u, ~0u};
    unsigned int lmax[4] = {0u, 0u, 0u, 0u};
#pragma unroll
    for (int h = 0; h < 2; ++h) {
#pragma unroll
        for (int j = 0; j < 16; ++j) {
            unsigned int base = ((unsigned int)rc[h].b[j]) << 8;
            unsigned int v0 = base + rm[h].b[j];
            unsigned int v1 = base + (j ? rm[h].b[j - 1] : (h ? rm[0].b[15] : pm));
            unsigned int v2 = base + (j ? rc[h].b[j - 1] : (h ? rc[0].b[15] : pc));
            unsigned int v3 = base + (j ? rp[h].b[j - 1] : (h ? rp[0].b[15] : pp));
            lmin[0] = min(lmin[0], v0); lmax[0] = max(lmax[0], v0);
            lmin[1] = min(lmin[1], v1); lmax[1] = max(lmax[1], v1);
            lmin[2] = min(lmin[2], v2); lmax[2] = max(lmax[2], v2);
            lmin[3] = min(lmin[3], v3); lmax[3] = max(lmax[3], v3);
        }
    }
#pragma unroll
    for (int off = 32; off > 0; off >>= 1) {
#pragma unroll
        for (int s = 0; s < 4; ++s) {
            lmin[s] = min(lmin[s], (unsigned int)__shfl_down((int)lmin[s], off));
            lmax[s] = max(lmax[s], (unsigned int)__shfl_down((int)lmax[s], off));
        }
    }
    __shared__ unsigned int wmin[4][4], wmax[4][4];
    int wave = threadIdx.x >> 6;
    if ((threadIdx.x & 63) == 0) {
#pragma unroll
        for (int s = 0; s < 4; ++s) { wmin[wave][s] = lmin[s]; wmax[wave][s] = lmax[s]; }
    }
    __syncthreads();
    if (threadIdx.x < 4) {
        int s = threadIdx.x;
        unsigned int mn = min(min(wmin[0][s], wmin[1][s]), min(wmin[2][s], wmin[3][s]));
        unsigned int mx = max(max(wmax[0][s], wmax[1][s]), max(wmax[2][s], wmax[3][s]));
        blockmm[inp * 4096 + s * 512 + blockIdx.x] = mn;
        blockmm[inp * 4096 + (4 + s) * 512 + blockIdx.x] = mx;
    }
}

__global__ __launch_bounds__(256) void k2_contrast(
    const uchar4* __restrict__ gray, const unsigned int* __restrict__ blockmm,
    unsigned int* __restrict__ partial) {
    int inp = blockIdx.y;
    int img = blockIdx.x >> 5;
    int r0 = (blockIdx.x & 31) << 4;

    __shared__ unsigned char lds[18 * W];
    __shared__ unsigned int mmfin[8];
    uchar4* lds4 = (uchar4*)lds;
    const uchar4* gin = gray + (size_t)inp * (NPIX / 4) + img * 65536;

#pragma unroll
    for (int j = 0; j < 9; ++j) {
        int q = threadIdx.x + j * 256;
        int i = q >> 7, quad = q & 127;
        int ir = (r0 - 1 + i) & 511;
        lds4[q] = gin[ir * 128 + quad];
    }
    {
        int s8 = threadIdx.x >> 5, lane = threadIdx.x & 31;
        const unsigned int* mb = blockmm + inp * 4096 + s8 * 512;
        unsigned int v = mb[lane];
#pragma unroll
        for (int k = 1; k < 16; ++k) {
            unsigned int u = mb[lane + k * 32];
            v = (s8 < 4) ? min(v, u) : max(v, u);
        }
#pragma unroll
        for (int off = 16; off > 0; off >>= 1) {
            unsigned int u = (unsigned int)__shfl_down((int)v, off, 32);
            v = (s8 < 4) ? min(v, u) : max(v, u);
        }
        if (lane == 0) mmfin[s8] = v;
    }
    __syncthreads();

    unsigned int vm[4]; float scale[4];
#pragma unroll
    for (int s = 0; s < 4; ++s) {
        vm[s] = mmfin[s];
        scale[s] = 65536.0f / fmaxf((float)(mmfin[4 + s] - vm[s]), 1.0f);
    }

    int lr = 1 + (threadIdx.x >> 4);
    int c0 = (threadIdx.x & 15) << 5;
    const unsigned char* Lm = lds + (lr - 1) * W;
    const unsigned char* Lc = lds + lr * W;
    const unsigned char* Lp = lds + (lr + 1) * W;
    Bytes rm[2], rc[2], rp[2];
    rm[0].v = *(const uint4*)(Lm + c0); rm[1].v = *(const uint4*)(Lm + c0 + 16);
    rc[0].v = *(const uint4*)(Lc + c0); rc[1].v = *(const uint4*)(Lc + c0 + 16);
    rp[0].v = *(const uint4*)(Lp + c0); rp[1].v = *(const uint4*)(Lp + c0 + 16);
    int cp = (c0 - 1) & 511;
    unsigned char pm = Lm[cp], pc = Lc[cp], pp = Lp[cp];

    unsigned int acc[4] = {0u, 0u, 0u, 0u};
#pragma unroll
    for (int h = 0; h < 2; ++h) {
#pragma unroll
        for (int j = 0; j < 16; ++j) {
            unsigned int base = ((unsigned int)rc[h].b[j]) << 8;
            unsigned int v[4];
            v[0] = base + rm[h].b[j];
            v[1] = base + (j ? rm[h].b[j - 1] : (h ? rm[0].b[15] : pm));
            v[2] = base + (j ? rc[h].b[j - 1] : (h ? rc[0].b[15] : pc));
            v[3] = base + (j ? rp[h].b[j - 1] : (h ? rp[0].b[15] : pp));
#pragma unroll
            for (int s = 0; s < 4; ++s) {
                int b = (int)floorf((float)(v[s] - vm[s]) * scale[s]);
                b = b < 0 ? 0 : (b > 65535 ? 65535 : b);
                int d = (b >> 8) - (b & 255);
                acc[s] += (unsigned int)(d * d);
            }
        }
    }
#pragma unroll
    for (int off = 32; off > 0; off >>= 1)
#pragma unroll
        for (int s = 0; s < 4; ++s)
            acc[s] += (unsigned int)__shfl_down((int)acc[s], off);

    __shared__ unsigned int wsum[4][4];
    int wave = threadIdx.x >> 6;
    if ((threadIdx.x & 63) == 0) {
#pragma unroll
        for (int s = 0; s < 4; ++s) wsum[wave][s] = acc[s];
    }
    __syncthreads();
    if (threadIdx.x < 4) {
        int s = threadIdx.x;
        unsigned int tot = wsum[0][s] + wsum[1][s] + wsum[2][s] + wsum[3][s];
        partial[(inp * 4 + s) * 512 + blockIdx.x] = tot;
    }
}

__global__ __launch_bounds__(256) void k3_loss(
    const unsigned int* __restrict__ partial, float* __restrict__ out) {
    int c = threadIdx.x >> 5;
    int lane = threadIdx.x & 31;
    const unsigned int* p = partial + c * 512;
    double acc = 0.0;
#pragma unroll
    for (int k = 0; k < 16; ++k) acc += (double)p[lane + k * 32];
#pragma unroll
    for (int off = 16; off > 0; off >>= 1) acc += __shfl_down(acc, off, 32);
    __shared__ double cs[8];
    if (lane == 0) cs[c] = acc;
    __syncthreads();
    if (threadIdx.x == 0) {
        double r = 0.0;
        for (int a = 0; a < 4; ++a) {
            double co = 2.0 * cs[a]     / 33554432.0;
            double cg = 2.0 * cs[4 + a] / 33554432.0;
            r += fabs(co - cg);
        }
        out[0] = (float)(r * 0.25);
    }
}

extern "C" void kernel_launch(void* const* d_in, const int* in_sizes, int n_in,
                              void* d_out, int out_size, void* d_ws, size_t ws_size,
                              hipStream_t stream) {
    const float4* og = (const float4*)d_in[0];
    const float4* gg = (const float4*)d_in[1];
    float* out = (float*)d_out;

    // ws: blockmm u32[8192] @0 | partial u32[4096] @32KB | gray (fallback) @64KB
    unsigned int* blockmm = (unsigned int*)d_ws;
    unsigned int* partial = blockmm + 8192;
    uchar4* gray = (uchar4*)((char*)d_ws + 65536);

    void* args[] = {(void*)&og, (void*)&gg, (void*)&blockmm,
                    (void*)&partial, (void*)&out};
    hipError_t err = hipLaunchCooperativeKernel((void*)fused, dim3(512), dim3(256),
                                                args, 0, stream);
    if (err != hipSuccess) {
        // deterministic fallback: R5's proven 3-kernel path
        dim3 grid(512, 2);
        k1_gray_minmax<<<grid, 256, 0, stream>>>(og, gg, gray, blockmm);
        k2_contrast<<<grid, 256, 0, stream>>>(gray, blockmm, partial);
        k3_loss<<<1, 256, 0, stream>>>(partial, out);
    }
}

// Round 8
// 52.189 us; speedup vs baseline: 4.7591x; 4.7591x over previous
//
#include <hip/hip_runtime.h>

#define W 512
#define NPIX 4194304              // 16 images * 512*512, per input

union Bytes { uint4 v; unsigned char b[16]; };

__device__ __forceinline__ unsigned char gray1(float a, float b, float c) {
    // JAX f32 op order: ((c0+c1+c2)/3)*255, round-nearest-even
    return (unsigned char)__float2int_rn(((a + b + c) / 3.0f) * 255.0f);
}

// ---------------------------------------------------------------------------
// K1: per block = one 16-row tile of one image of one input (grid 512 x 2).
//   - gray rows r0-1..r0+16 (18 rows incl. recomputed halo) -> LDS
//   - store main 16 rows to global gray buffer
//   - per-block min/max of joint = center*256 + shifted, 4 shifts
//     SHIFTS=(1,0),(1,1),(0,1),(-1,1); shifted[r,c]=g[(r-dx)&511,(c-dy)&511]
//   - 8 u32 per block to distinct global slots (no atomics)
//   - block (0,0) thread 0 resets the k2 finalize ticket counter
// Proven at ~6.4 TB/s in R5 — unchanged except the counter reset.
// ---------------------------------------------------------------------------
__global__ __launch_bounds__(256) void k1_gray_minmax(
    const float4* __restrict__ og, const float4* __restrict__ gg,
    uchar4* __restrict__ gray, unsigned int* __restrict__ blockmm,
    unsigned int* __restrict__ counter) {
    if (blockIdx.x == 0 && blockIdx.y == 0 && threadIdx.x == 0) *counter = 0u;

    int inp = blockIdx.y;
    int img = blockIdx.x >> 5;
    int r0 = (blockIdx.x & 31) << 4;
    const float4* src = (inp ? gg : og) + (size_t)img * 3 * 65536;
    uchar4* gout = gray + (size_t)inp * (NPIX / 4) + img * 65536;

    __shared__ unsigned char lds[18 * W];
    uchar4* lds4 = (uchar4*)lds;
#pragma unroll
    for (int j = 0; j < 9; ++j) {
        int q = threadIdx.x + j * 256;          // 18 rows * 128 quads
        int i = q >> 7, quad = q & 127;
        int ir = (r0 - 1 + i) & 511;
        float4 a = src[(size_t)ir * 128 + quad];
        float4 b = src[65536 + (size_t)ir * 128 + quad];
        float4 c = src[131072 + (size_t)ir * 128 + quad];
        uchar4 r;
        r.x = gray1(a.x, b.x, c.x);
        r.y = gray1(a.y, b.y, c.y);
        r.z = gray1(a.z, b.z, c.z);
        r.w = gray1(a.w, b.w, c.w);
        lds4[q] = r;
        if (i >= 1 && i <= 16) gout[ir * 128 + quad] = r;   // main rows only
    }
    __syncthreads();

    // each thread: 32 px of one center row (lds rows 1..16)
    int lr = 1 + (threadIdx.x >> 4);
    int c0 = (threadIdx.x & 15) << 5;
    const unsigned char* Lm = lds + (lr - 1) * W;
    const unsigned char* Lc = lds + lr * W;
    const unsigned char* Lp = lds + (lr + 1) * W;
    Bytes rm[2], rc[2], rp[2];
    rm[0].v = *(const uint4*)(Lm + c0); rm[1].v = *(const uint4*)(Lm + c0 + 16);
    rc[0].v = *(const uint4*)(Lc + c0); rc[1].v = *(const uint4*)(Lc + c0 + 16);
    rp[0].v = *(const uint4*)(Lp + c0); rp[1].v = *(const uint4*)(Lp + c0 + 16);
    int cp = (c0 - 1) & 511;
    unsigned char pm = Lm[cp], pc = Lc[cp], pp = Lp[cp];

    unsigned int lmin[4] = {~0u, ~0u, ~0u, ~0u};
    unsigned int lmax[4] = {0u, 0u, 0u, 0u};
#pragma unroll
    for (int h = 0; h < 2; ++h) {
#pragma unroll
        for (int j = 0; j < 16; ++j) {
            unsigned int base = ((unsigned int)rc[h].b[j]) << 8;
            unsigned int v0 = base + rm[h].b[j];
            unsigned int v1 = base + (j ? rm[h].b[j - 1] : (h ? rm[0].b[15] : pm));
            unsigned int v2 = base + (j ? rc[h].b[j - 1] : (h ? rc[0].b[15] : pc));
            unsigned int v3 = base + (j ? rp[h].b[j - 1] : (h ? rp[0].b[15] : pp));
            lmin[0] = min(lmin[0], v0); lmax[0] = max(lmax[0], v0);
            lmin[1] = min(lmin[1], v1); lmax[1] = max(lmax[1], v1);
            lmin[2] = min(lmin[2], v2); lmax[2] = max(lmax[2], v2);
            lmin[3] = min(lmin[3], v3); lmax[3] = max(lmax[3], v3);
        }
    }
#pragma unroll
    for (int off = 32; off > 0; off >>= 1) {
#pragma unroll
        for (int s = 0; s < 4; ++s) {
            lmin[s] = min(lmin[s], (unsigned int)__shfl_down((int)lmin[s], off));
            lmax[s] = max(lmax[s], (unsigned int)__shfl_down((int)lmax[s], off));
        }
    }
    __shared__ unsigned int wmin[4][4], wmax[4][4];
    int wave = threadIdx.x >> 6;
    if ((threadIdx.x & 63) == 0) {
#pragma unroll
        for (int s = 0; s < 4; ++s) { wmin[wave][s] = lmin[s]; wmax[wave][s] = lmax[s]; }
    }
    __syncthreads();
    if (threadIdx.x < 4) {
        int s = threadIdx.x;
        unsigned int mn = min(min(wmin[0][s], wmin[1][s]), min(wmin[2][s], wmin[3][s]));
        unsigned int mx = max(max(wmax[0][s], wmax[1][s]), max(wmax[2][s], wmax[3][s]));
        blockmm[inp * 4096 + s * 512 + blockIdx.x] = mn;
        blockmm[inp * 4096 + (4 + s) * 512 + blockIdx.x] = mx;
    }
}

// ---------------------------------------------------------------------------
// K2: per block = same tile mapping (grid 512 x 2).
//   - redundantly reduce this input's 512x8 block-minmax table (L2-resident)
//   - load gray tile+halo (18 rows) from global -> LDS
//   - per-pixel: t = (float)(v - vmin); b = min((int)(t*scale), 65535)
//     [t >= 0 always, so (int) truncation == floor and no lower clamp]
//     d = (b>>8)-(b&255); accumulate d^2 in u32
//   - write 4 per-block partial sums to distinct slots
//   - last-arriving block (device ticket) reduces all 8x512 partials
//     (double, exact) and writes the loss. Ticket reset by k1 each call.
// ---------------------------------------------------------------------------
__global__ __launch_bounds__(256) void k2_contrast_final(
    const uchar4* __restrict__ gray, const unsigned int* __restrict__ blockmm,
    unsigned int* __restrict__ partial, unsigned int* __restrict__ counter,
    float* __restrict__ out) {
    int inp = blockIdx.y;
    int img = blockIdx.x >> 5;
    int r0 = (blockIdx.x & 31) << 4;

    __shared__ unsigned char lds[18 * W];
    __shared__ unsigned int mmfin[8];
    __shared__ unsigned int ticket;
    __shared__ double cs[8];
    uchar4* lds4 = (uchar4*)lds;
    const uchar4* gin = gray + (size_t)inp * (NPIX / 4) + img * 65536;

#pragma unroll
    for (int j = 0; j < 9; ++j) {
        int q = threadIdx.x + j * 256;
        int i = q >> 7, quad = q & 127;
        int ir = (r0 - 1 + i) & 511;
        lds4[q] = gin[ir * 128 + quad];
    }
    // reduce block-minmax table: 8 groups of 32 lanes, 16 values each
    {
        int s8 = threadIdx.x >> 5, lane = threadIdx.x & 31;
        const unsigned int* mb = blockmm + inp * 4096 + s8 * 512;
        unsigned int v = mb[lane];
#pragma unroll
        for (int k = 1; k < 16; ++k) {
            unsigned int u = mb[lane + k * 32];
            v = (s8 < 4) ? min(v, u) : max(v, u);
        }
#pragma unroll
        for (int off = 16; off > 0; off >>= 1) {
            unsigned int u = (unsigned int)__shfl_down((int)v, off, 32);
            v = (s8 < 4) ? min(v, u) : max(v, u);
        }
        if (lane == 0) mmfin[s8] = v;
    }
    __syncthreads();

    unsigned int vm[4]; float scale[4];
#pragma unroll
    for (int s = 0; s < 4; ++s) {
        vm[s] = mmfin[s];
        scale[s] = 65536.0f / fmaxf((float)(mmfin[4 + s] - vm[s]), 1.0f);
    }

    int lr = 1 + (threadIdx.x >> 4);
    int c0 = (threadIdx.x & 15) << 5;
    const unsigned char* Lm = lds + (lr - 1) * W;
    const unsigned char* Lc = lds + lr * W;
    const unsigned char* Lp = lds + (lr + 1) * W;
    Bytes rm[2], rc[2], rp[2];
    rm[0].v = *(const uint4*)(Lm + c0); rm[1].v = *(const uint4*)(Lm + c0 + 16);
    rc[0].v = *(const uint4*)(Lc + c0); rc[1].v = *(const uint4*)(Lc + c0 + 16);
    rp[0].v = *(const uint4*)(Lp + c0); rp[1].v = *(const uint4*)(Lp + c0 + 16);
    int cp = (c0 - 1) & 511;
    unsigned char pm = Lm[cp], pc = Lc[cp], pp = Lp[cp];

    unsigned int acc[4] = {0u, 0u, 0u, 0u};
#pragma unroll
    for (int h = 0; h < 2; ++h) {
#pragma unroll
        for (int j = 0; j < 16; ++j) {
            unsigned int base = ((unsigned int)rc[h].b[j]) << 8;
            unsigned int v[4];
            v[0] = base + rm[h].b[j];
            v[1] = base + (j ? rm[h].b[j - 1] : (h ? rm[0].b[15] : pm));
            v[2] = base + (j ? rc[h].b[j - 1] : (h ? rc[0].b[15] : pc));
            v[3] = base + (j ? rp[h].b[j - 1] : (h ? rp[0].b[15] : pp));
#pragma unroll
            for (int s = 0; s < 4; ++s) {
                int b = (int)((float)(v[s] - vm[s]) * scale[s]);  // t>=0: trunc==floor
                b = b > 65535 ? 65535 : b;
                int d = (b >> 8) - (b & 255);
                acc[s] += (unsigned int)(d * d);
            }
        }
    }
#pragma unroll
    for (int off = 32; off > 0; off >>= 1)
#pragma unroll
        for (int s = 0; s < 4; ++s)
            acc[s] += (unsigned int)__shfl_down((int)acc[s], off);

    __shared__ unsigned int wsum[4][4];
    int wave = threadIdx.x >> 6;
    if ((threadIdx.x & 63) == 0) {
#pragma unroll
        for (int s = 0; s < 4; ++s) wsum[wave][s] = acc[s];
    }
    __syncthreads();
    if (threadIdx.x < 4) {
        int s = threadIdx.x;
        unsigned int tot = wsum[0][s] + wsum[1][s] + wsum[2][s] + wsum[3][s];
        partial[(inp * 4 + s) * 512 + blockIdx.x] = tot;
    }

    // ---- last-block finalize (1024 blocks total) ----
    __syncthreads();                     // partial stores ordered before fence
    if (threadIdx.x == 0) {
        __threadfence();                 // release partials device-wide
        ticket = atomicAdd(counter, 1u);
    }
    __syncthreads();
    if (ticket == 1023u) {
        __threadfence();                 // acquire all blocks' partials
        int c = threadIdx.x >> 5;        // combo = inp*4 + s
        int lane = threadIdx.x & 31;
        const unsigned int* p = partial + c * 512;
        double a2 = 0.0;
#pragma unroll
        for (int k = 0; k < 16; ++k) a2 += (double)p[lane + k * 32];
#pragma unroll
        for (int off = 16; off > 0; off >>= 1) a2 += __shfl_down(a2, off, 32);
        if (lane == 0) cs[c] = a2;
        __syncthreads();
        if (threadIdx.x == 0) {
            double r = 0.0;
            for (int a = 0; a < 4; ++a) {
                double co = 2.0 * cs[a]     / 33554432.0;
                double cg = 2.0 * cs[4 + a] / 33554432.0;
                r += fabs(co - cg);
            }
            out[0] = (float)(r * 0.25);
        }
    }
}

extern "C" void kernel_launch(void* const* d_in, const int* in_sizes, int n_in,
                              void* d_out, int out_size, void* d_ws, size_t ws_size,
                              hipStream_t stream) {
    const float4* og = (const float4*)d_in[0];
    const float4* gg = (const float4*)d_in[1];
    float* out = (float*)d_out;

    // ws: blockmm u32[8192] @0 (32KB) | partial u32[4096] @32KB (16KB)
    //     | counter u32 @48KB | gray @64KB (8MB)
    unsigned int* blockmm = (unsigned int*)d_ws;
    unsigned int* partial = blockmm + 8192;
    unsigned int* counter = (unsigned int*)((char*)d_ws + 49152);
    uchar4* gray = (uchar4*)((char*)d_ws + 65536);

    dim3 grid(512, 2);
    k1_gray_minmax<<<grid, 256, 0, stream>>>(og, gg, gray, blockmm, counter);
    k2_contrast_final<<<grid, 256, 0, stream>>>(gray, blockmm, partial, counter, out);
}

// Round 9
// 45.086 us; speedup vs baseline: 5.5089x; 1.1576x over previous
//
#include <hip/hip_runtime.h>

#define W 512
#define NPIX 4194304              // 16 images * 512*512, per input

union Bytes { uint4 v; unsigned char b[16]; };

__device__ __forceinline__ unsigned char gray1(float a, float b, float c) {
    // JAX f32 op order: ((c0+c1+c2)/3)*255, round-nearest-even
    return (unsigned char)__float2int_rn(((a + b + c) / 3.0f) * 255.0f);
}

// ---------------------------------------------------------------------------
// K1: per block = one 8-row tile of one image of one input (grid 1024 x 2 =
// 2048 blocks -> 8 blocks/CU, launch_bounds(256,8) caps VGPR<=64 so all are
// resident; R8 showed 16-row/4-block version was latency-bound at 34% occ).
//   - gray rows r0-1..r0+8 (10 rows incl. recomputed halo) -> LDS
//   - store main 8 rows to global gray buffer
//   - per-block min/max of joint = center*256 + shifted, 4 shifts
//     SHIFTS=(1,0),(1,1),(0,1),(-1,1); shifted[r,c]=g[(r-dx)&511,(c-dy)&511]
//   - 8 u32 per block to distinct global slots (no atomics)
// ---------------------------------------------------------------------------
__global__ __launch_bounds__(256, 8) void k1_gray_minmax(
    const float4* __restrict__ og, const float4* __restrict__ gg,
    uchar4* __restrict__ gray, unsigned int* __restrict__ blockmm) {
    int inp = blockIdx.y;
    int img = blockIdx.x >> 6;              // 64 tiles per image
    int r0 = (blockIdx.x & 63) << 3;        // 8-row tile
    const float4* src = (inp ? gg : og) + (size_t)img * 3 * 65536;
    uchar4* gout = gray + (size_t)inp * (NPIX / 4) + img * 65536;

    __shared__ unsigned char lds[10 * W];
    uchar4* lds4 = (uchar4*)lds;
#pragma unroll
    for (int j = 0; j < 5; ++j) {
        int q = threadIdx.x + j * 256;      // 10 rows * 128 quads = 1280
        int i = q >> 7, quad = q & 127;
        int ir = (r0 - 1 + i) & 511;
        float4 a = src[(size_t)ir * 128 + quad];
        float4 b = src[65536 + (size_t)ir * 128 + quad];
        float4 c = src[131072 + (size_t)ir * 128 + quad];
        uchar4 r;
        r.x = gray1(a.x, b.x, c.x);
        r.y = gray1(a.y, b.y, c.y);
        r.z = gray1(a.z, b.z, c.z);
        r.w = gray1(a.w, b.w, c.w);
        lds4[q] = r;
        if (i >= 1 && i <= 8) gout[ir * 128 + quad] = r;   // main rows only
    }
    __syncthreads();

    // each thread: 16 px of one center row (lds rows 1..8)
    int lr = 1 + (threadIdx.x >> 5);
    int c0 = (threadIdx.x & 31) << 4;
    const unsigned char* Lm = lds + (lr - 1) * W;
    const unsigned char* Lc = lds + lr * W;
    const unsigned char* Lp = lds + (lr + 1) * W;
    Bytes rm, rc, rp;
    rm.v = *(const uint4*)(Lm + c0);
    rc.v = *(const uint4*)(Lc + c0);
    rp.v = *(const uint4*)(Lp + c0);
    int cp = (c0 - 1) & 511;
    unsigned char pm = Lm[cp], pc = Lc[cp], pp = Lp[cp];

    unsigned int lmin[4] = {~0u, ~0u, ~0u, ~0u};
    unsigned int lmax[4] = {0u, 0u, 0u, 0u};
#pragma unroll
    for (int j = 0; j < 16; ++j) {
        unsigned int base = ((unsigned int)rc.b[j]) << 8;
        unsigned int v0 = base + rm.b[j];
        unsigned int v1 = base + (j ? rm.b[j - 1] : pm);
        unsigned int v2 = base + (j ? rc.b[j - 1] : pc);
        unsigned int v3 = base + (j ? rp.b[j - 1] : pp);
        lmin[0] = min(lmin[0], v0); lmax[0] = max(lmax[0], v0);
        lmin[1] = min(lmin[1], v1); lmax[1] = max(lmax[1], v1);
        lmin[2] = min(lmin[2], v2); lmax[2] = max(lmax[2], v2);
        lmin[3] = min(lmin[3], v3); lmax[3] = max(lmax[3], v3);
    }
#pragma unroll
    for (int off = 32; off > 0; off >>= 1) {
#pragma unroll
        for (int s = 0; s < 4; ++s) {
            lmin[s] = min(lmin[s], (unsigned int)__shfl_down((int)lmin[s], off));
            lmax[s] = max(lmax[s], (unsigned int)__shfl_down((int)lmax[s], off));
        }
    }
    __shared__ unsigned int wmin[4][4], wmax[4][4];
    int wave = threadIdx.x >> 6;
    if ((threadIdx.x & 63) == 0) {
#pragma unroll
        for (int s = 0; s < 4; ++s) { wmin[wave][s] = lmin[s]; wmax[wave][s] = lmax[s]; }
    }
    __syncthreads();
    if (threadIdx.x < 4) {
        int s = threadIdx.x;
        unsigned int mn = min(min(wmin[0][s], wmin[1][s]), min(wmin[2][s], wmin[3][s]));
        unsigned int mx = max(max(wmax[0][s], wmax[1][s]), max(wmax[2][s], wmax[3][s]));
        blockmm[inp * 8192 + s * 1024 + blockIdx.x] = mn;
        blockmm[inp * 8192 + (4 + s) * 1024 + blockIdx.x] = mx;
    }
}

// ---------------------------------------------------------------------------
// K2: per block = same 8-row tile mapping (grid 1024 x 2).
//   - redundantly reduce this input's 1024x8 block-minmax table (L2-resident)
//   - load gray tile+halo (10 rows) from global -> LDS
//   - per-pixel: t = (float)(v - vmin); b = min((int)(t*scale), 65535)
//     [t >= 0 always, so (int) truncation == floor and no lower clamp]
//     d = (b>>8)-(b&255); accumulate d^2 in u32
//   - write 4 per-block partial sums to distinct slots (no atomics)
// ---------------------------------------------------------------------------
__global__ __launch_bounds__(256, 8) void k2_contrast(
    const uchar4* __restrict__ gray, const unsigned int* __restrict__ blockmm,
    unsigned int* __restrict__ partial) {
    int inp = blockIdx.y;
    int img = blockIdx.x >> 6;
    int r0 = (blockIdx.x & 63) << 3;

    __shared__ unsigned char lds[10 * W];
    __shared__ unsigned int mmfin[8];
    uchar4* lds4 = (uchar4*)lds;
    const uchar4* gin = gray + (size_t)inp * (NPIX / 4) + img * 65536;

#pragma unroll
    for (int j = 0; j < 5; ++j) {
        int q = threadIdx.x + j * 256;
        int i = q >> 7, quad = q & 127;
        int ir = (r0 - 1 + i) & 511;
        lds4[q] = gin[ir * 128 + quad];
    }
    // reduce block-minmax table: 8 groups of 32 lanes, 32 values each
    {
        int s8 = threadIdx.x >> 5, lane = threadIdx.x & 31;
        const unsigned int* mb = blockmm + inp * 8192 + s8 * 1024;
        unsigned int v = mb[lane];
#pragma unroll
        for (int k = 1; k < 32; ++k) {
            unsigned int u = mb[lane + k * 32];
            v = (s8 < 4) ? min(v, u) : max(v, u);
        }
#pragma unroll
        for (int off = 16; off > 0; off >>= 1) {
            unsigned int u = (unsigned int)__shfl_down((int)v, off, 32);
            v = (s8 < 4) ? min(v, u) : max(v, u);
        }
        if (lane == 0) mmfin[s8] = v;
    }
    __syncthreads();

    unsigned int vm[4]; float scale[4];
#pragma unroll
    for (int s = 0; s < 4; ++s) {
        vm[s] = mmfin[s];
        scale[s] = 65536.0f / fmaxf((float)(mmfin[4 + s] - vm[s]), 1.0f);
    }

    int lr = 1 + (threadIdx.x >> 5);
    int c0 = (threadIdx.x & 31) << 4;
    const unsigned char* Lm = lds + (lr - 1) * W;
    const unsigned char* Lc = lds + lr * W;
    const unsigned char* Lp = lds + (lr + 1) * W;
    Bytes rm, rc, rp;
    rm.v = *(const uint4*)(Lm + c0);
    rc.v = *(const uint4*)(Lc + c0);
    rp.v = *(const uint4*)(Lp + c0);
    int cp = (c0 - 1) & 511;
    unsigned char pm = Lm[cp], pc = Lc[cp], pp = Lp[cp];

    unsigned int acc[4] = {0u, 0u, 0u, 0u};
#pragma unroll
    for (int j = 0; j < 16; ++j) {
        unsigned int base = ((unsigned int)rc.b[j]) << 8;
        unsigned int v[4];
        v[0] = base + rm.b[j];
        v[1] = base + (j ? rm.b[j - 1] : pm);
        v[2] = base + (j ? rc.b[j - 1] : pc);
        v[3] = base + (j ? rp.b[j - 1] : pp);
#pragma unroll
        for (int s = 0; s < 4; ++s) {
            int b = (int)((float)(v[s] - vm[s]) * scale[s]);  // t>=0: trunc==floor
            b = b > 65535 ? 65535 : b;
            int d = (b >> 8) - (b & 255);
            acc[s] += (unsigned int)(d * d);
        }
    }
#pragma unroll
    for (int off = 32; off > 0; off >>= 1)
#pragma unroll
        for (int s = 0; s < 4; ++s)
            acc[s] += (unsigned int)__shfl_down((int)acc[s], off);

    __shared__ unsigned int wsum[4][4];
    int wave = threadIdx.x >> 6;
    if ((threadIdx.x & 63) == 0) {
#pragma unroll
        for (int s = 0; s < 4; ++s) wsum[wave][s] = acc[s];
    }
    __syncthreads();
    if (threadIdx.x < 4) {
        int s = threadIdx.x;
        unsigned int tot = wsum[0][s] + wsum[1][s] + wsum[2][s] + wsum[3][s];
        partial[(inp * 4 + s) * 1024 + blockIdx.x] = tot;
    }
}

// ---------------------------------------------------------------------------
// K3: one block. Reduce 8 combos x 1024 partials (double, exact < 2^53),
// loss = mean_a |2*S_og/2^25 - 2*S_gg/2^25|
// ---------------------------------------------------------------------------
__global__ __launch_bounds__(256) void k3_loss(
    const unsigned int* __restrict__ partial, float* __restrict__ out) {
    int c = threadIdx.x >> 5;       // combo = inp*4 + s
    int lane = threadIdx.x & 31;
    const unsigned int* p = partial + c * 1024;
    double acc = 0.0;
#pragma unroll
    for (int k = 0; k < 32; ++k) acc += (double)p[lane + k * 32];
#pragma unroll
    for (int off = 16; off > 0; off >>= 1) acc += __shfl_down(acc, off, 32);
    __shared__ double cs[8];
    if (lane == 0) cs[c] = acc;
    __syncthreads();
    if (threadIdx.x == 0) {
        double r = 0.0;
        for (int a = 0; a < 4; ++a) {
            double co = 2.0 * cs[a]     / 33554432.0;
            double cg = 2.0 * cs[4 + a] / 33554432.0;
            r += fabs(co - cg);
        }
        out[0] = (float)(r * 0.25);
    }
}

extern "C" void kernel_launch(void* const* d_in, const int* in_sizes, int n_in,
                              void* d_out, int out_size, void* d_ws, size_t ws_size,
                              hipStream_t stream) {
    const float4* og = (const float4*)d_in[0];
    const float4* gg = (const float4*)d_in[1];
    float* out = (float*)d_out;

    // ws: blockmm u32[16384] @0 (64KB) | partial u32[8192] @64KB (32KB)
    //     | gray @128KB (8MB)
    unsigned int* blockmm = (unsigned int*)d_ws;
    unsigned int* partial = blockmm + 16384;
    uchar4* gray = (uchar4*)((char*)d_ws + 131072);

    dim3 grid(1024, 2);
    k1_gray_minmax<<<grid, 256, 0, stream>>>(og, gg, gray, blockmm);
    k2_contrast<<<grid, 256, 0, stream>>>(gray, blockmm, partial);
    k3_loss<<<1, 256, 0, stream>>>(partial, out);
}

// Round 10
// 40.623 us; speedup vs baseline: 6.1141x; 1.1099x over previous
//
#include <hip/hip_runtime.h>

#define W 512
#define NPIX 4194304              // 16 images * 512*512, per input

union Bytes { uint4 v; unsigned char b[16]; };

__device__ __forceinline__ unsigned char gray1(float a, float b, float c) {
    // JAX f32 op order: ((c0+c1+c2)/3)*255, round-nearest-even
    return (unsigned char)__float2int_rn(((a + b + c) / 3.0f) * 255.0f);
}

// ---------------------------------------------------------------------------
// K1: per block = one 16-row tile of one image of one input (grid 512 x 2,
// = 4 blocks/CU, grid-capped). launch_bounds(256,4) -> VGPR cap 128 so the
// staging loop can software-pipeline (R8 showed VGPR=32 serialized every
// load behind a waitcnt -> latency-bound at 16% VALU).
//   - gray rows r0-1..r0+16 (18 rows incl. recomputed halo) -> LDS,
//     prefetch-depth-1 pipelined loads
//   - store main 16 rows to global gray buffer
//   - per-block min/max of joint = center*256 + shifted, 4 shifts
//     SHIFTS=(1,0),(1,1),(0,1),(-1,1); shifted[r,c]=g[(r-dx)&511,(c-dy)&511]
//   - 8 u32 per block to distinct global slots (no atomics)
// ---------------------------------------------------------------------------
__global__ __launch_bounds__(256, 4) void k1_gray_minmax(
    const float4* __restrict__ og, const float4* __restrict__ gg,
    uchar4* __restrict__ gray, unsigned int* __restrict__ blockmm) {
    int inp = blockIdx.y;
    int img = blockIdx.x >> 5;
    int r0 = (blockIdx.x & 31) << 4;
    const float4* src = (inp ? gg : og) + (size_t)img * 3 * 65536;
    uchar4* gout = gray + (size_t)inp * (NPIX / 4) + img * 65536;
    const float4* s0 = src;
    const float4* s1 = src + 65536;
    const float4* s2 = src + 131072;

    __shared__ unsigned char lds[18 * W];
    uchar4* lds4 = (uchar4*)lds;

    // offsets for the 9 staging iterations (18 rows * 128 quads / 256 thr)
    int off[9];
#pragma unroll
    for (int j = 0; j < 9; ++j) {
        int q = threadIdx.x + j * 256;
        int i = q >> 7, quad = q & 127;
        int ir = (r0 - 1 + i) & 511;
        off[j] = ir * 128 + quad;
    }
    // software pipeline, prefetch distance 1
    float4 a = s0[off[0]], b = s1[off[0]], c = s2[off[0]];
#pragma unroll
    for (int j = 0; j < 9; ++j) {
        float4 an, bn, cn;
        if (j < 8) { an = s0[off[j + 1]]; bn = s1[off[j + 1]]; cn = s2[off[j + 1]]; }
        uchar4 r;
        r.x = gray1(a.x, b.x, c.x);
        r.y = gray1(a.y, b.y, c.y);
        r.z = gray1(a.z, b.z, c.z);
        r.w = gray1(a.w, b.w, c.w);
        lds4[threadIdx.x + j * 256] = r;
        int i = (threadIdx.x + j * 256) >> 7;
        if (i >= 1 && i <= 16) gout[off[j]] = r;   // main rows only
        a = an; b = bn; c = cn;
    }
    __syncthreads();

    // each thread: 32 px of one center row (lds rows 1..16)
    int lr = 1 + (threadIdx.x >> 4);
    int c0 = (threadIdx.x & 15) << 5;
    const unsigned char* Lm = lds + (lr - 1) * W;
    const unsigned char* Lc = lds + lr * W;
    const unsigned char* Lp = lds + (lr + 1) * W;
    Bytes rm[2], rc[2], rp[2];
    rm[0].v = *(const uint4*)(Lm + c0); rm[1].v = *(const uint4*)(Lm + c0 + 16);
    rc[0].v = *(const uint4*)(Lc + c0); rc[1].v = *(const uint4*)(Lc + c0 + 16);
    rp[0].v = *(const uint4*)(Lp + c0); rp[1].v = *(const uint4*)(Lp + c0 + 16);
    int cp = (c0 - 1) & 511;
    unsigned char pm = Lm[cp], pc = Lc[cp], pp = Lp[cp];

    unsigned int lmin[4] = {~0u, ~0u, ~0u, ~0u};
    unsigned int lmax[4] = {0u, 0u, 0u, 0u};
#pragma unroll
    for (int h = 0; h < 2; ++h) {
#pragma unroll
        for (int j = 0; j < 16; ++j) {
            unsigned int base = ((unsigned int)rc[h].b[j]) << 8;
            unsigned int v0 = base + rm[h].b[j];
            unsigned int v1 = base + (j ? rm[h].b[j - 1] : (h ? rm[0].b[15] : pm));
            unsigned int v2 = base + (j ? rc[h].b[j - 1] : (h ? rc[0].b[15] : pc));
            unsigned int v3 = base + (j ? rp[h].b[j - 1] : (h ? rp[0].b[15] : pp));
            lmin[0] = min(lmin[0], v0); lmax[0] = max(lmax[0], v0);
            lmin[1] = min(lmin[1], v1); lmax[1] = max(lmax[1], v1);
            lmin[2] = min(lmin[2], v2); lmax[2] = max(lmax[2], v2);
            lmin[3] = min(lmin[3], v3); lmax[3] = max(lmax[3], v3);
        }
    }
#pragma unroll
    for (int off2 = 32; off2 > 0; off2 >>= 1) {
#pragma unroll
        for (int s = 0; s < 4; ++s) {
            lmin[s] = min(lmin[s], (unsigned int)__shfl_down((int)lmin[s], off2));
            lmax[s] = max(lmax[s], (unsigned int)__shfl_down((int)lmax[s], off2));
        }
    }
    __shared__ unsigned int wmin[4][4], wmax[4][4];
    int wave = threadIdx.x >> 6;
    if ((threadIdx.x & 63) == 0) {
#pragma unroll
        for (int s = 0; s < 4; ++s) { wmin[wave][s] = lmin[s]; wmax[wave][s] = lmax[s]; }
    }
    __syncthreads();
    if (threadIdx.x < 4) {
        int s = threadIdx.x;
        unsigned int mn = min(min(wmin[0][s], wmin[1][s]), min(wmin[2][s], wmin[3][s]));
        unsigned int mx = max(max(wmax[0][s], wmax[1][s]), max(wmax[2][s], wmax[3][s]));
        blockmm[inp * 4096 + s * 512 + blockIdx.x] = mn;
        blockmm[inp * 4096 + (4 + s) * 512 + blockIdx.x] = mx;
    }
}

// ---------------------------------------------------------------------------
// K2: per block = same tile mapping (grid 512 x 2).
//   - redundantly reduce this input's 512x8 block-minmax table (L2-resident)
//   - load gray tile+halo (18 rows) from global -> LDS, pipelined
//   - per-pixel: t = (float)(v - vmin); b = min((int)(t*scale), 65535)
//     [t >= 0 always, so (int) truncation == floor and no lower clamp]
//     d = (b>>8)-(b&255); accumulate d^2 in u32
//   - write 4 per-block partial sums to distinct slots (no atomics)
// ---------------------------------------------------------------------------
__global__ __launch_bounds__(256, 4) void k2_contrast(
    const uchar4* __restrict__ gray, const unsigned int* __restrict__ blockmm,
    unsigned int* __restrict__ partial) {
    int inp = blockIdx.y;
    int img = blockIdx.x >> 5;
    int r0 = (blockIdx.x & 31) << 4;

    __shared__ unsigned char lds[18 * W];
    __shared__ unsigned int mmfin[8];
    uchar4* lds4 = (uchar4*)lds;
    const uchar4* gin = gray + (size_t)inp * (NPIX / 4) + img * 65536;

    int off[9];
#pragma unroll
    for (int j = 0; j < 9; ++j) {
        int q = threadIdx.x + j * 256;
        int i = q >> 7, quad = q & 127;
        int ir = (r0 - 1 + i) & 511;
        off[j] = ir * 128 + quad;
    }
    uchar4 g0 = gin[off[0]];
#pragma unroll
    for (int j = 0; j < 9; ++j) {
        uchar4 gn;
        if (j < 8) gn = gin[off[j + 1]];
        lds4[threadIdx.x + j * 256] = g0;
        g0 = gn;
    }
    // reduce block-minmax table: 8 groups of 32 lanes, 16 values each
    {
        int s8 = threadIdx.x >> 5, lane = threadIdx.x & 31;
        const unsigned int* mb = blockmm + inp * 4096 + s8 * 512;
        unsigned int v = mb[lane];
#pragma unroll
        for (int k = 1; k < 16; ++k) {
            unsigned int u = mb[lane + k * 32];
            v = (s8 < 4) ? min(v, u) : max(v, u);
        }
#pragma unroll
        for (int off2 = 16; off2 > 0; off2 >>= 1) {
            unsigned int u = (unsigned int)__shfl_down((int)v, off2, 32);
            v = (s8 < 4) ? min(v, u) : max(v, u);
        }
        if (lane == 0) mmfin[s8] = v;
    }
    __syncthreads();

    unsigned int vm[4]; float scale[4];
#pragma unroll
    for (int s = 0; s < 4; ++s) {
        vm[s] = mmfin[s];
        scale[s] = 65536.0f / fmaxf((float)(mmfin[4 + s] - vm[s]), 1.0f);
    }

    int lr = 1 + (threadIdx.x >> 4);
    int c0 = (threadIdx.x & 15) << 5;
    const unsigned char* Lm = lds + (lr - 1) * W;
    const unsigned char* Lc = lds + lr * W;
    const unsigned char* Lp = lds + (lr + 1) * W;
    Bytes rm[2], rc[2], rp[2];
    rm[0].v = *(const uint4*)(Lm + c0); rm[1].v = *(const uint4*)(Lm + c0 + 16);
    rc[0].v = *(const uint4*)(Lc + c0); rc[1].v = *(const uint4*)(Lc + c0 + 16);
    rp[0].v = *(const uint4*)(Lp + c0); rp[1].v = *(const uint4*)(Lp + c0 + 16);
    int cp = (c0 - 1) & 511;
    unsigned char pm = Lm[cp], pc = Lc[cp], pp = Lp[cp];

    unsigned int acc[4] = {0u, 0u, 0u, 0u};
#pragma unroll
    for (int h = 0; h < 2; ++h) {
#pragma unroll
        for (int j = 0; j < 16; ++j) {
            unsigned int base = ((unsigned int)rc[h].b[j]) << 8;
            unsigned int v[4];
            v[0] = base + rm[h].b[j];
            v[1] = base + (j ? rm[h].b[j - 1] : (h ? rm[0].b[15] : pm));
            v[2] = base + (j ? rc[h].b[j - 1] : (h ? rc[0].b[15] : pc));
            v[3] = base + (j ? rp[h].b[j - 1] : (h ? rp[0].b[15] : pp));
#pragma unroll
            for (int s = 0; s < 4; ++s) {
                int b = (int)((float)(v[s] - vm[s]) * scale[s]);  // t>=0: trunc==floor
                b = b > 65535 ? 65535 : b;
                int d = (b >> 8) - (b & 255);
                acc[s] += (unsigned int)(d * d);
            }
        }
    }
#pragma unroll
    for (int off2 = 32; off2 > 0; off2 >>= 1)
#pragma unroll
        for (int s = 0; s < 4; ++s)
            acc[s] += (unsigned int)__shfl_down((int)acc[s], off2);

    __shared__ unsigned int wsum[4][4];
    int wave = threadIdx.x >> 6;
    if ((threadIdx.x & 63) == 0) {
#pragma unroll
        for (int s = 0; s < 4; ++s) wsum[wave][s] = acc[s];
    }
    __syncthreads();
    if (threadIdx.x < 4) {
        int s = threadIdx.x;
        unsigned int tot = wsum[0][s] + wsum[1][s] + wsum[2][s] + wsum[3][s];
        partial[(inp * 4 + s) * 512 + blockIdx.x] = tot;
    }
}

// ---------------------------------------------------------------------------
// K3: one block. Reduce 8 combos x 512 partials (double, exact < 2^53),
// loss = mean_a |2*S_og/2^25 - 2*S_gg/2^25|
// ---------------------------------------------------------------------------
__global__ __launch_bounds__(256) void k3_loss(
    const unsigned int* __restrict__ partial, float* __restrict__ out) {
    int c = threadIdx.x >> 5;       // combo = inp*4 + s
    int lane = threadIdx.x & 31;
    const unsigned int* p = partial + c * 512;
    double acc = 0.0;
#pragma unroll
    for (int k = 0; k < 16; ++k) acc += (double)p[lane + k * 32];
#pragma unroll
    for (int off = 16; off > 0; off >>= 1) acc += __shfl_down(acc, off, 32);
    __shared__ double cs[8];
    if (lane == 0) cs[c] = acc;
    __syncthreads();
    if (threadIdx.x == 0) {
        double r = 0.0;
        for (int a = 0; a < 4; ++a) {
            double co = 2.0 * cs[a]     / 33554432.0;
            double cg = 2.0 * cs[4 + a] / 33554432.0;
            r += fabs(co - cg);
        }
        out[0] = (float)(r * 0.25);
    }
}

extern "C" void kernel_launch(void* const* d_in, const int* in_sizes, int n_in,
                              void* d_out, int out_size, void* d_ws, size_t ws_size,
                              hipStream_t stream) {
    const float4* og = (const float4*)d_in[0];
    const float4* gg = (const float4*)d_in[1];
    float* out = (float*)d_out;

    // ws: blockmm u32[8192] @0 (32KB) | partial u32[4096] @32KB (16KB)
    //     | gray @64KB (8MB)
    unsigned int* blockmm = (unsigned int*)d_ws;
    unsigned int* partial = blockmm + 8192;
    uchar4* gray = (uchar4*)((char*)d_ws + 65536);

    dim3 grid(512, 2);
    k1_gray_minmax<<<grid, 256, 0, stream>>>(og, gg, gray, blockmm);
    k2_contrast<<<grid, 256, 0, stream>>>(gray, blockmm, partial);
    k3_loss<<<1, 256, 0, stream>>>(partial, out);
}